// Round 11
// baseline (1962.115 us; speedup 1.0000x reference)
//
#include <hip/hip_runtime.h>
#include <hip/hip_bf16.h>

// 2-layer LSTM (T=1024, B=512, IN=20, H1=128, H2=64) + head OUT=3.
// Only batch row 511 feeds the output => single-sequence scan.
//
// Pipeline:
//   A : xp1 = x[:,511,:] @ W_ih0^T + b0            (parallel)
//   B1: layer-1 scan — f16 weights in LDS + v_dot2 (serial, 1 CU)
//   C1: xp2 = h1seq @ W_ih1^T + b1                 (parallel GEMM)
//   B2: layer-2 scan — same scheme                  (serial, 1 CU)
//   D : head                                        (parallel)
//
// Round-11: weights live in LDS as f16 (W_hh0=128KB fits; 340B/cyc/CU vs
// L2's 110), consumed via v_dot2_f32_f16 (2 MACs/instr, f32 accum). Rows
// padded to 17/9 chunks -> bank-start 4(g+j)%32 -> conflict-free, no addr
// math. h is split hi/lo f16 (lo scaled x4096 vs denorm flush) so the only
// quantization is W's (~2^-12 relative): absmax ~1e-4 << 2.9e-3.
// This sidesteps the register-allocator remat war (R3-R7), the AGPR
// readback cost (R9), and the MFMA broadcast waste (R10) entirely.

#define T_STEPS 1024
#define BATCH   512
#define IN_F    20
#define H1_     128
#define H2_     64
#define OUT_F   3
#define G1_     (4*H1_)   // 512
#define G2_     (4*H2_)   // 256

typedef float f4 __attribute__((ext_vector_type(4)));
typedef unsigned int u32;
typedef u32 u4 __attribute__((ext_vector_type(4)));
typedef _Float16 h2 __attribute__((ext_vector_type(2)));

__device__ __forceinline__ float sigmoidf_(float x) {
    return 1.0f / (1.0f + __expf(-x));
}
__device__ __forceinline__ float tanhf_(float x) {
    return 1.0f - 2.0f / (__expf(2.0f * x) + 1.0f);
}
__device__ __forceinline__ h2 as_h2(u32 v) {
    union { u32 u; h2 h; } c; c.u = v; return c.h;
}
__device__ __forceinline__ u32 pkh(float a, float b) {
    union { _Float16 h[2]; u32 u; } c;
    c.h[0] = (_Float16)a; c.h[1] = (_Float16)b; return c.u;
}
__device__ __forceinline__ float fdot2_(h2 a, h2 b, float c) {
#if __has_builtin(__builtin_amdgcn_fdot2)
    return __builtin_amdgcn_fdot2(a, b, c, false);
#else
    float d = c;
    asm("v_dot2_f32_f16 %0, %1, %2, %0" : "+v"(d) : "v"(a), "v"(b));
    return d;
#endif
}

// ---------------- A: x-projection for batch row 511 --------------------------
__global__ void xproj_kernel(const float* __restrict__ x,
                             const float* __restrict__ W_ih0,
                             const float* __restrict__ b_ih0,
                             const float* __restrict__ b_hh0,
                             float* __restrict__ xp1)
{
    const int t = blockIdx.x;
    const int g = threadIdx.x;
    const float* xr = x + ((size_t)t * BATCH + (BATCH - 1)) * IN_F;
    const float* w  = W_ih0 + g * IN_F;
    float acc = b_ih0[g] + b_hh0[g];
#pragma unroll
    for (int i = 0; i < IN_F; ++i) acc = fmaf(xr[i], w[i], acc);
    xp1[t * G1_ + g] = acc;
}

// ---------------- B1: layer-1 scan (serial, one block) -----------------------
// 512 threads = 8 waves (2/SIMD). Thread g owns gate g (full 128-dot).
// W_hh0 rows as f16 pairs in LDS, 17-chunk padded stride (conflict-free).
// h split: hi f16 + lo f16 (scaled 4096). 128 fdot2 + 48 ds_read/thread/step.
__global__ __attribute__((amdgpu_flat_work_group_size(512, 512),
                          amdgpu_waves_per_eu(2, 2)))
void lstm1_kernel(const float* __restrict__ xp1,
                  const float* __restrict__ W_hh0,
                  float* __restrict__ h1seq)
{
    const int tid = threadIdx.x;      // gate index g

    __shared__ u4    swW[512 * 17];   // W f16 pairs, padded rows (136 KB)
    __shared__ u4    shhi[16];        // h_hi  f16[128]
    __shared__ u4    shlo[16];        // h_lo*4096 f16[128]
    __shared__ float sg[G1_];         // gate pre-activations

    // ---- one-time: convert W row g to f16 pairs in LDS ---------------------
    {
        const float* wr = W_hh0 + (size_t)tid * H1_;
#pragma unroll
        for (int j = 0; j < 16; ++j) {
            const f4 lo = *(const f4*)(wr + j * 8);
            const f4 hi = *(const f4*)(wr + j * 8 + 4);
            u4 pk;
            pk.x = pkh(lo.x, lo.y);
            pk.y = pkh(lo.z, lo.w);
            pk.z = pkh(hi.x, hi.y);
            pk.w = pkh(hi.z, hi.w);
            swW[tid * 17 + j] = pk;
        }
    }
    if (tid < 16) { shhi[tid] = u4{0,0,0,0}; shlo[tid] = u4{0,0,0,0}; }
    float c1 = 0.0f;                  // owned by tid < 128
    __syncthreads();

    const u4* wrow = swW + tid * 17;
    float xp_cur = xp1[tid];

    for (int t = 0; t < T_STEPS; ++t) {
        float xp_next;
        {
            const int tn = (t + 1 < T_STEPS) ? (t + 1) : (T_STEPS - 1);
            xp_next = xp1[(size_t)tn * G1_ + tid];
        }

        // ---- gate g = xp + W[g].h  (hi terms in a0/a1, lo-scaled in a2/a3) --
        float a0 = 0.f, a1 = 0.f, a2 = 0.f, a3 = 0.f;
#pragma unroll
        for (int j = 0; j < 16; ++j) {
            const u4 wq = wrow[j];
            const u4 hh = shhi[j];
            const u4 hl = shlo[j];
            a0 = fdot2_(as_h2(wq.x), as_h2(hh.x), a0);
            a1 = fdot2_(as_h2(wq.y), as_h2(hh.y), a1);
            a0 = fdot2_(as_h2(wq.z), as_h2(hh.z), a0);
            a1 = fdot2_(as_h2(wq.w), as_h2(hh.w), a1);
            a2 = fdot2_(as_h2(wq.x), as_h2(hl.x), a2);
            a3 = fdot2_(as_h2(wq.y), as_h2(hl.y), a3);
            a2 = fdot2_(as_h2(wq.z), as_h2(hl.z), a2);
            a3 = fdot2_(as_h2(wq.w), as_h2(hl.w), a3);
        }
        sg[tid] = ((a0 + a1) + 0.000244140625f * (a2 + a3)) + xp_cur;
        __syncthreads();   // sg ready (also orders prev h stores)

        // ---- pointwise (tid<128): c1, h, store f32 + f16 hi/lo --------------
        if (tid < H1_) {
            const float vi = sg[tid];
            const float vf = sg[H1_ + tid];
            const float vg = sg[2 * H1_ + tid];
            const float vo = sg[3 * H1_ + tid];
            c1 = fmaf(sigmoidf_(vf), c1, sigmoidf_(vi) * tanhf_(vg));
            const float h = sigmoidf_(vo) * tanhf_(c1);
            const _Float16 hh16 = (_Float16)h;
            const float hrem = (h - (float)hh16) * 4096.0f;
            ((_Float16*)shhi)[tid] = hh16;
            ((_Float16*)shlo)[tid] = (_Float16)hrem;
            h1seq[(size_t)t * H1_ + tid] = h;   // fire-and-forget (f32 state)
        }
        __syncthreads();   // h f16 arrays ready
        xp_cur = xp_next;
    }
}

// ---------------- C1: xp2 = h1seq @ W_ih1^T + (b_ih1 + b_hh1) ---------------
__global__ void xproj2_kernel(const float* __restrict__ h1seq,
                              const float* __restrict__ W_ih1,
                              const float* __restrict__ b_ih1,
                              const float* __restrict__ b_hh1,
                              float* __restrict__ xp2)
{
    const int t = blockIdx.x;
    const int g = threadIdx.x;
    __shared__ f4 sh[H1_ / 4];
    if (g < H1_ / 4) sh[g] = ((const f4*)(h1seq + (size_t)t * H1_))[g];
    __syncthreads();
    const f4* w = (const f4*)(W_ih1 + (size_t)g * H1_);
    float ax = 0.f, ay = 0.f, az = 0.f, aw = 0.f;
#pragma unroll
    for (int k = 0; k < H1_ / 4; ++k) {
        const f4 h4 = sh[k]; const f4 w4 = w[k];
        ax = fmaf(w4.x, h4.x, ax); ay = fmaf(w4.y, h4.y, ay);
        az = fmaf(w4.z, h4.z, az); aw = fmaf(w4.w, h4.w, aw);
    }
    xp2[(size_t)t * G2_ + g] = ((ax + ay) + (az + aw)) + b_ih1[g] + b_hh1[g];
}

// ---------------- B2: layer-2 scan (serial, one block) -----------------------
// 256 threads = 4 waves (1/SIMD). Thread g owns gate g (full 64-dot).
// W_hh1 f16 in LDS, 9-chunk padded stride. Same hi/lo h scheme.
__global__ __attribute__((amdgpu_flat_work_group_size(256, 256),
                          amdgpu_waves_per_eu(1, 1)))
void lstm2_kernel(const float* __restrict__ xp2,
                  const float* __restrict__ W_hh1,
                  float* __restrict__ h2seq)
{
    const int tid = threadIdx.x;      // gate index

    __shared__ u4    swW2[256 * 9];   // W f16 pairs, padded rows (36 KB)
    __shared__ u4    shhi[8];         // h_hi  f16[64]
    __shared__ u4    shlo[8];         // h_lo*4096 f16[64]
    __shared__ float sg2[G2_];

    {
        const float* wr = W_hh1 + (size_t)tid * H2_;
#pragma unroll
        for (int j = 0; j < 8; ++j) {
            const f4 lo = *(const f4*)(wr + j * 8);
            const f4 hi = *(const f4*)(wr + j * 8 + 4);
            u4 pk;
            pk.x = pkh(lo.x, lo.y);
            pk.y = pkh(lo.z, lo.w);
            pk.z = pkh(hi.x, hi.y);
            pk.w = pkh(hi.z, hi.w);
            swW2[tid * 9 + j] = pk;
        }
    }
    if (tid < 8) { shhi[tid] = u4{0,0,0,0}; shlo[tid] = u4{0,0,0,0}; }
    float c2 = 0.0f;                  // owned by tid < 64
    __syncthreads();

    const u4* wrow = swW2 + tid * 9;
    float xp_cur = xp2[tid];

    for (int t = 0; t < T_STEPS; ++t) {
        float xp_next;
        {
            const int tn = (t + 1 < T_STEPS) ? (t + 1) : (T_STEPS - 1);
            xp_next = xp2[(size_t)tn * G2_ + tid];
        }

        float a0 = 0.f, a1 = 0.f, a2 = 0.f, a3 = 0.f;
#pragma unroll
        for (int j = 0; j < 8; ++j) {
            const u4 wq = wrow[j];
            const u4 hh = shhi[j];
            const u4 hl = shlo[j];
            a0 = fdot2_(as_h2(wq.x), as_h2(hh.x), a0);
            a1 = fdot2_(as_h2(wq.y), as_h2(hh.y), a1);
            a0 = fdot2_(as_h2(wq.z), as_h2(hh.z), a0);
            a1 = fdot2_(as_h2(wq.w), as_h2(hh.w), a1);
            a2 = fdot2_(as_h2(wq.x), as_h2(hl.x), a2);
            a3 = fdot2_(as_h2(wq.y), as_h2(hl.y), a3);
            a2 = fdot2_(as_h2(wq.z), as_h2(hl.z), a2);
            a3 = fdot2_(as_h2(wq.w), as_h2(hl.w), a3);
        }
        sg2[tid] = ((a0 + a1) + 0.000244140625f * (a2 + a3)) + xp_cur;
        __syncthreads();   // sg2 ready (also orders prev h stores)

        if (tid < H2_) {
            const float vi = sg2[tid];
            const float vf = sg2[H2_ + tid];
            const float vg = sg2[2 * H2_ + tid];
            const float vo = sg2[3 * H2_ + tid];
            c2 = fmaf(sigmoidf_(vf), c2, sigmoidf_(vi) * tanhf_(vg));
            const float h = sigmoidf_(vo) * tanhf_(c2);
            const _Float16 hh16 = (_Float16)h;
            const float hrem = (h - (float)hh16) * 4096.0f;
            ((_Float16*)shhi)[tid] = hh16;
            ((_Float16*)shlo)[tid] = (_Float16)hrem;
            h2seq[(size_t)t * H2_ + tid] = h;
        }
        __syncthreads();
        xp_cur = xp_next;
    }
}

// ---------------- D: head out[t,o] = relu(h2[t]) . W_d[o] + b_d --------------
__global__ void head_kernel(const float* __restrict__ h2seq,
                            const float* __restrict__ W_d,
                            const float* __restrict__ b_d,
                            float* __restrict__ out)
{
    const int idx = blockIdx.x * blockDim.x + threadIdx.x;
    if (idx >= T_STEPS * OUT_F) return;
    const int t = idx / OUT_F;
    const int o = idx - t * OUT_F;
    const float* hr = h2seq + (size_t)t * H2_;
    const float* w  = W_d + o * H2_;
    float acc = b_d[o];
#pragma unroll
    for (int j = 0; j < H2_; ++j) acc = fmaf(fmaxf(hr[j], 0.0f), w[j], acc);
    out[idx] = acc;
}

extern "C" void kernel_launch(void* const* d_in, const int* in_sizes, int n_in,
                              void* d_out, int out_size, void* d_ws, size_t ws_size,
                              hipStream_t stream) {
    const float* x     = (const float*)d_in[0];
    const float* W_ih0 = (const float*)d_in[1];
    const float* W_hh0 = (const float*)d_in[2];
    const float* b_ih0 = (const float*)d_in[3];
    const float* b_hh0 = (const float*)d_in[4];
    const float* W_ih1 = (const float*)d_in[5];
    const float* W_hh1 = (const float*)d_in[6];
    const float* b_ih1 = (const float*)d_in[7];
    const float* b_hh1 = (const float*)d_in[8];
    const float* W_d   = (const float*)d_in[9];
    const float* b_d   = (const float*)d_in[10];

    float* out   = (float*)d_out;
    float* xp1   = (float*)d_ws;                       // [1024][512] = 2 MB
    float* h1seq = xp1 + (size_t)T_STEPS * G1_;        // [1024][128] = 512 KB
    float* h2seq = h1seq + (size_t)T_STEPS * H1_;      // [1024][64]  = 256 KB
    float* xp2   = xp1;                                // overlay (xp1 dead after B1)

    hipLaunchKernelGGL(xproj_kernel, dim3(T_STEPS), dim3(G1_), 0, stream,
                       x, W_ih0, b_ih0, b_hh0, xp1);
    hipLaunchKernelGGL(lstm1_kernel, dim3(1), dim3(512), 0, stream,
                       xp1, W_hh0, h1seq);
    hipLaunchKernelGGL(xproj2_kernel, dim3(T_STEPS), dim3(G2_), 0, stream,
                       h1seq, W_ih1, b_ih1, b_hh1, xp2);
    hipLaunchKernelGGL(lstm2_kernel, dim3(1), dim3(256), 0, stream,
                       xp2, W_hh1, h2seq);
    hipLaunchKernelGGL(head_kernel, dim3((T_STEPS * OUT_F + 255) / 256), dim3(256),
                       0, stream, h2seq, W_d, b_d, out);
}

// Round 12
// 1674.740 us; speedup vs baseline: 1.1716x; 1.1716x over previous
//
#include <hip/hip_runtime.h>
#include <hip/hip_bf16.h>

// 2-layer LSTM (T=1024, B=512, IN=20, H1=128, H2=64) + head OUT=3.
// Only batch row 511 feeds the output => single-sequence scan.
//
// Pipeline:
//   A : xp1 = x[:,511,:] @ W_ih0^T + b0            (parallel)
//   P : pack W_hh0/W_hh1 high-quads to f16 global  (parallel, once)
//   B1: layer-1 scan — W split LDS+global, fdot2   (serial, 1 CU)
//   C1: xp2 = h1seq @ W_ih1^T + b1                 (parallel GEMM)
//   B2: layer-2 scan — same scheme                  (serial, 1 CU)
//   D : head                                        (parallel)
//
// Round-12: R11 was LDS-BW bound (131KB f16 W/step = 1024 bank-cyc floor,
// 2 waves/SIMD -> latency bubbles -> 2900 cyc/step). Now: 1024 threads
// (4 waves/SIMD), W split 50/50 between LDS (64KB, stride-5 conflict-free)
// and plain loads of a pre-packed f16 buffer (register-resident or L1/L2
// stream — either outcome is a second pipe in parallel with LDS).
// Numerics unchanged from R11: f16 W, exact hi/lo-f16 h (lo scaled 4096).

#define T_STEPS 1024
#define BATCH   512
#define IN_F    20
#define H1_     128
#define H2_     64
#define OUT_F   3
#define G1_     (4*H1_)   // 512
#define G2_     (4*H2_)   // 256

typedef float f4 __attribute__((ext_vector_type(4)));
typedef unsigned int u32;
typedef u32 u4 __attribute__((ext_vector_type(4)));
typedef _Float16 h2t __attribute__((ext_vector_type(2)));

__device__ __forceinline__ float sigmoidf_(float x) {
    return 1.0f / (1.0f + __expf(-x));
}
__device__ __forceinline__ float tanhf_(float x) {
    return 1.0f - 2.0f / (__expf(2.0f * x) + 1.0f);
}
__device__ __forceinline__ h2t as_h2(u32 v) {
    union { u32 u; h2t h; } c; c.u = v; return c.h;
}
__device__ __forceinline__ u32 pkh(float a, float b) {
    union { _Float16 h[2]; u32 u; } c;
    c.h[0] = (_Float16)a; c.h[1] = (_Float16)b; return c.u;
}
__device__ __forceinline__ float fdot2_(h2t a, h2t b, float c) {
#if __has_builtin(__builtin_amdgcn_fdot2)
    return __builtin_amdgcn_fdot2(a, b, c, false);
#else
    float d = c;
    asm("v_dot2_f32_f16 %0, %1, %2, %0" : "+v"(d) : "v"(a), "v"(b));
    return d;
#endif
}
__device__ __forceinline__ u4 packq(const float* p) {
    const f4 a = *(const f4*)p;
    const f4 b = *(const f4*)(p + 4);
    u4 pk;
    pk.x = pkh(a.x, a.y); pk.y = pkh(a.z, a.w);
    pk.z = pkh(b.x, b.y); pk.w = pkh(b.z, b.w);
    return pk;
}

#define LO_SCALE_INV 0.000244140625f   // 2^-12

// 8 fdot2 against one W quad (hi accum a0/a1, scaled-lo accum a2/a3)
#define DOTQ(WQ, HH, HL)                                                      \
    { const u4 hh_ = (HH); const u4 hl_ = (HL);                               \
      a0 = fdot2_(as_h2((WQ).x), as_h2(hh_.x), a0);                           \
      a1 = fdot2_(as_h2((WQ).y), as_h2(hh_.y), a1);                           \
      a0 = fdot2_(as_h2((WQ).z), as_h2(hh_.z), a0);                           \
      a1 = fdot2_(as_h2((WQ).w), as_h2(hh_.w), a1);                           \
      a2 = fdot2_(as_h2((WQ).x), as_h2(hl_.x), a2);                           \
      a3 = fdot2_(as_h2((WQ).y), as_h2(hl_.y), a3);                           \
      a2 = fdot2_(as_h2((WQ).z), as_h2(hl_.z), a2);                           \
      a3 = fdot2_(as_h2((WQ).w), as_h2(hl_.w), a3); }

// ---------------- A: x-projection for batch row 511 --------------------------
__global__ void xproj_kernel(const float* __restrict__ x,
                             const float* __restrict__ W_ih0,
                             const float* __restrict__ b_ih0,
                             const float* __restrict__ b_hh0,
                             float* __restrict__ xp1)
{
    const int t = blockIdx.x;
    const int g = threadIdx.x;
    const float* xr = x + ((size_t)t * BATCH + (BATCH - 1)) * IN_F;
    const float* w  = W_ih0 + g * IN_F;
    float acc = b_ih0[g] + b_hh0[g];
#pragma unroll
    for (int i = 0; i < IN_F; ++i) acc = fmaf(xr[i], w[i], acc);
    xp1[t * G1_ + g] = acc;
}

// ---------------- P: pack high W quads to f16 global -------------------------
// pack1: r in [0,1024), qq in [0,4): g=r&511, hf=r>>9, cols hf*64+32+8qq
// pack2: r2 in [0,512), qq in [0,2): g2=r2&255, hf=r2>>8, cols hf*32+16+8qq
__global__ void pack_kernel(const float* __restrict__ W_hh0,
                            const float* __restrict__ W_hh1,
                            u4* __restrict__ wpk1,
                            u4* __restrict__ wpk2)
{
    const int idx = blockIdx.x * blockDim.x + threadIdx.x;
    if (idx < 4096) {
        const int r = idx >> 2, qq = idx & 3;
        const int g = r & 511, hf = r >> 9;
        wpk1[r * 4 + qq] = packq(W_hh0 + (size_t)g * H1_ + hf * 64 + 32 + 8 * qq);
    } else if (idx < 4096 + 1024) {
        const int i2 = idx - 4096;
        const int r2 = i2 >> 1, qq = i2 & 1;
        const int g2 = r2 & 255, hf = r2 >> 8;
        wpk2[r2 * 2 + qq] = packq(W_hh1 + (size_t)g2 * H2_ + hf * 32 + 16 + 8 * qq);
    }
}

// ---------------- B1: layer-1 scan (serial, one block) -----------------------
// 1024 thr = 16 waves (4/SIMD). Thread (g=tid&511, hf=tid>>9) owns 64 weights:
// quads 0..3 from LDS (stride-5, conflict-free), quads 4..7 from wpk1 (plain
// loads: reg-resident or L1/L2 stream). Partials sp1[g*2+hf]; 2 barriers/step.
__global__ __attribute__((amdgpu_flat_work_group_size(1024, 1024),
                          amdgpu_waves_per_eu(4, 4)))
void lstm1_kernel(const float* __restrict__ xp1,
                  const float* __restrict__ W_hh0,
                  const u4* __restrict__ wpk1,
                  float* __restrict__ h1seq)
{
    const int tid = threadIdx.x;
    const int g   = tid & 511;
    const int hf  = tid >> 9;          // wave-uniform
    const int r   = hf * 512 + g;      // LDS W row (lane step = 5 u4 -> no conflict)

    __shared__ u4    swW[1024 * 5];    // 80 KB: W quads 0..3, padded stride 5
    __shared__ u4    shhi[16];         // h_hi  f16[128]
    __shared__ u4    shlo[16];         // h_lo*4096 f16[128]
    __shared__ float sp1[1024];        // partials [g*2+hf] (4 KB)

    // ---- one-time: stage low-half W quads as f16 pairs ---------------------
    {
        const float* wr = W_hh0 + (size_t)g * H1_ + hf * 64;
#pragma unroll
        for (int q = 0; q < 4; ++q) swW[r * 5 + q] = packq(wr + q * 8);
    }
    if (tid < 16) { shhi[tid] = u4{0,0,0,0}; shlo[tid] = u4{0,0,0,0}; }
    float c1 = 0.0f;                   // owned by tid < 128
    __syncthreads();

    const u4* wk = wpk1 + (size_t)r * 4;   // quads 4..7 (loop-invariant addr)
    float xp_cur = (hf == 0) ? xp1[g] : 0.0f;

    for (int t = 0; t < T_STEPS; ++t) {
        float xp_next = 0.0f;
        if (hf == 0) {
            const int tn = (t + 1 < T_STEPS) ? (t + 1) : (T_STEPS - 1);
            xp_next = xp1[(size_t)tn * G1_ + g];
        }
        // global-path W quads (compiler keeps in regs or re-streams via L1/L2)
        const u4 w4_ = wk[0], w5_ = wk[1], w6_ = wk[2], w7_ = wk[3];

        float a0 = 0.f, a1 = 0.f, a2 = 0.f, a3 = 0.f;
#pragma unroll
        for (int q = 0; q < 4; ++q) {
            const u4 wq = swW[r * 5 + q];
            DOTQ(wq, shhi[hf * 8 + q], shlo[hf * 8 + q]);
        }
        DOTQ(w4_, shhi[hf * 8 + 4], shlo[hf * 8 + 4]);
        DOTQ(w5_, shhi[hf * 8 + 5], shlo[hf * 8 + 5]);
        DOTQ(w6_, shhi[hf * 8 + 6], shlo[hf * 8 + 6]);
        DOTQ(w7_, shhi[hf * 8 + 7], shlo[hf * 8 + 7]);

        sp1[g * 2 + hf] = ((a0 + a1) + LO_SCALE_INV * (a2 + a3)) + xp_cur;
        __syncthreads();   // partials ready (also orders prev h stores)

        // ---- pointwise (tid<128): combine halves, activate, publish h ------
        if (tid < H1_) {
            const float vi = sp1[tid * 2]              + sp1[tid * 2 + 1];
            const float vf = sp1[(H1_ + tid) * 2]      + sp1[(H1_ + tid) * 2 + 1];
            const float vg = sp1[(2 * H1_ + tid) * 2]  + sp1[(2 * H1_ + tid) * 2 + 1];
            const float vo = sp1[(3 * H1_ + tid) * 2]  + sp1[(3 * H1_ + tid) * 2 + 1];
            c1 = fmaf(sigmoidf_(vf), c1, sigmoidf_(vi) * tanhf_(vg));
            const float h = sigmoidf_(vo) * tanhf_(c1);
            const _Float16 hh16 = (_Float16)h;
            const float hrem = (h - (float)hh16) * 4096.0f;
            ((_Float16*)shhi)[tid] = hh16;
            ((_Float16*)shlo)[tid] = (_Float16)hrem;
            h1seq[(size_t)t * H1_ + tid] = h;   // fire-and-forget (f32 state)
        }
        __syncthreads();   // h f16 arrays ready
        xp_cur = xp_next;
    }
}

// ---------------- C1: xp2 = h1seq @ W_ih1^T + (b_ih1 + b_hh1) ---------------
__global__ void xproj2_kernel(const float* __restrict__ h1seq,
                              const float* __restrict__ W_ih1,
                              const float* __restrict__ b_ih1,
                              const float* __restrict__ b_hh1,
                              float* __restrict__ xp2)
{
    const int t = blockIdx.x;
    const int g = threadIdx.x;
    __shared__ f4 sh[H1_ / 4];
    if (g < H1_ / 4) sh[g] = ((const f4*)(h1seq + (size_t)t * H1_))[g];
    __syncthreads();
    const f4* w = (const f4*)(W_ih1 + (size_t)g * H1_);
    float ax = 0.f, ay = 0.f, az = 0.f, aw = 0.f;
#pragma unroll
    for (int k = 0; k < H1_ / 4; ++k) {
        const f4 h4 = sh[k]; const f4 w4 = w[k];
        ax = fmaf(w4.x, h4.x, ax); ay = fmaf(w4.y, h4.y, ay);
        az = fmaf(w4.z, h4.z, az); aw = fmaf(w4.w, h4.w, aw);
    }
    xp2[(size_t)t * G2_ + g] = ((ax + ay) + (az + aw)) + b_ih1[g] + b_hh1[g];
}

// ---------------- B2: layer-2 scan (serial, one block) -----------------------
// 512 thr = 8 waves (2/SIMD). Thread (g2=tid&255, hf=tid>>8) owns 32 weights:
// quads 0..1 LDS (stride 3), quads 2..3 from wpk2. Partials sp2[g2*2+hf].
__global__ __attribute__((amdgpu_flat_work_group_size(512, 512),
                          amdgpu_waves_per_eu(2, 2)))
void lstm2_kernel(const float* __restrict__ xp2,
                  const float* __restrict__ W_hh1,
                  const u4* __restrict__ wpk2,
                  float* __restrict__ h2seq)
{
    const int tid = threadIdx.x;
    const int g2  = tid & 255;
    const int hf  = tid >> 8;          // wave-uniform
    const int r2  = hf * 256 + g2;     // lane step 3 u4 -> conflict-free

    __shared__ u4    swW2[512 * 3];    // 24 KB: W quads 0..1, stride 3
    __shared__ u4    shhi[8];          // h_hi  f16[64]
    __shared__ u4    shlo[8];          // h_lo*4096 f16[64]
    __shared__ float sp2[512];         // partials [g2*2+hf]

    {
        const float* wr = W_hh1 + (size_t)g2 * H2_ + hf * 32;
        swW2[r2 * 3 + 0] = packq(wr);
        swW2[r2 * 3 + 1] = packq(wr + 8);
    }
    if (tid < 8) { shhi[tid] = u4{0,0,0,0}; shlo[tid] = u4{0,0,0,0}; }
    float c2 = 0.0f;                   // owned by tid < 64
    __syncthreads();

    const u4* wk = wpk2 + (size_t)r2 * 2;
    float xp_cur = (hf == 0) ? xp2[g2] : 0.0f;

    for (int t = 0; t < T_STEPS; ++t) {
        float xp_next = 0.0f;
        if (hf == 0) {
            const int tn = (t + 1 < T_STEPS) ? (t + 1) : (T_STEPS - 1);
            xp_next = xp2[(size_t)tn * G2_ + g2];
        }
        const u4 w2_ = wk[0], w3_ = wk[1];

        float a0 = 0.f, a1 = 0.f, a2 = 0.f, a3 = 0.f;
        {
            const u4 wq0 = swW2[r2 * 3 + 0];
            DOTQ(wq0, shhi[hf * 4 + 0], shlo[hf * 4 + 0]);
            const u4 wq1 = swW2[r2 * 3 + 1];
            DOTQ(wq1, shhi[hf * 4 + 1], shlo[hf * 4 + 1]);
        }
        DOTQ(w2_, shhi[hf * 4 + 2], shlo[hf * 4 + 2]);
        DOTQ(w3_, shhi[hf * 4 + 3], shlo[hf * 4 + 3]);

        sp2[g2 * 2 + hf] = ((a0 + a1) + LO_SCALE_INV * (a2 + a3)) + xp_cur;
        __syncthreads();   // partials ready (also orders prev h stores)

        if (tid < H2_) {
            const float vi = sp2[tid * 2]              + sp2[tid * 2 + 1];
            const float vf = sp2[(H2_ + tid) * 2]      + sp2[(H2_ + tid) * 2 + 1];
            const float vg = sp2[(2 * H2_ + tid) * 2]  + sp2[(2 * H2_ + tid) * 2 + 1];
            const float vo = sp2[(3 * H2_ + tid) * 2]  + sp2[(3 * H2_ + tid) * 2 + 1];
            c2 = fmaf(sigmoidf_(vf), c2, sigmoidf_(vi) * tanhf_(vg));
            const float h = sigmoidf_(vo) * tanhf_(c2);
            const _Float16 hh16 = (_Float16)h;
            const float hrem = (h - (float)hh16) * 4096.0f;
            ((_Float16*)shhi)[tid] = hh16;
            ((_Float16*)shlo)[tid] = (_Float16)hrem;
            h2seq[(size_t)t * H2_ + tid] = h;
        }
        __syncthreads();
        xp_cur = xp_next;
    }
}

// ---------------- D: head out[t,o] = relu(h2[t]) . W_d[o] + b_d --------------
__global__ void head_kernel(const float* __restrict__ h2seq,
                            const float* __restrict__ W_d,
                            const float* __restrict__ b_d,
                            float* __restrict__ out)
{
    const int idx = blockIdx.x * blockDim.x + threadIdx.x;
    if (idx >= T_STEPS * OUT_F) return;
    const int t = idx / OUT_F;
    const int o = idx - t * OUT_F;
    const float* hr = h2seq + (size_t)t * H2_;
    const float* w  = W_d + o * H2_;
    float acc = b_d[o];
#pragma unroll
    for (int j = 0; j < H2_; ++j) acc = fmaf(fmaxf(hr[j], 0.0f), w[j], acc);
    out[idx] = acc;
}

extern "C" void kernel_launch(void* const* d_in, const int* in_sizes, int n_in,
                              void* d_out, int out_size, void* d_ws, size_t ws_size,
                              hipStream_t stream) {
    const float* x     = (const float*)d_in[0];
    const float* W_ih0 = (const float*)d_in[1];
    const float* W_hh0 = (const float*)d_in[2];
    const float* b_ih0 = (const float*)d_in[3];
    const float* b_hh0 = (const float*)d_in[4];
    const float* W_ih1 = (const float*)d_in[5];
    const float* W_hh1 = (const float*)d_in[6];
    const float* b_ih1 = (const float*)d_in[7];
    const float* b_hh1 = (const float*)d_in[8];
    const float* W_d   = (const float*)d_in[9];
    const float* b_d   = (const float*)d_in[10];

    float* out   = (float*)d_out;
    float* xp1   = (float*)d_ws;                       // [1024][512] = 2 MB
    float* h1seq = xp1 + (size_t)T_STEPS * G1_;        // [1024][128] = 512 KB
    float* h2seq = h1seq + (size_t)T_STEPS * H1_;      // [1024][64]  = 256 KB
    u4*    wpk1  = (u4*)(h2seq + (size_t)T_STEPS * H2_); // 1024*4*16B = 64 KB
    u4*    wpk2  = wpk1 + 1024 * 4;                      // 512*2*16B  = 16 KB
    float* xp2   = xp1;                                // overlay (xp1 dead after B1)

    hipLaunchKernelGGL(xproj_kernel, dim3(T_STEPS), dim3(G1_), 0, stream,
                       x, W_ih0, b_ih0, b_hh0, xp1);
    hipLaunchKernelGGL(pack_kernel, dim3(20), dim3(256), 0, stream,
                       W_hh0, W_hh1, wpk1, wpk2);
    hipLaunchKernelGGL(lstm1_kernel, dim3(1), dim3(1024), 0, stream,
                       xp1, W_hh0, wpk1, h1seq);
    hipLaunchKernelGGL(xproj2_kernel, dim3(T_STEPS), dim3(G2_), 0, stream,
                       h1seq, W_ih1, b_ih1, b_hh1, xp2);
    hipLaunchKernelGGL(lstm2_kernel, dim3(1), dim3(512), 0, stream,
                       xp2, W_hh1, wpk2, h2seq);
    hipLaunchKernelGGL(head_kernel, dim3((T_STEPS * OUT_F + 255) / 256), dim3(256),
                       0, stream, h2seq, W_d, b_d, out);
}

// Round 13
// 1624.913 us; speedup vs baseline: 1.2075x; 1.0307x over previous
//
#include <hip/hip_runtime.h>
#include <hip/hip_bf16.h>

// 2-layer LSTM (T=1024, B=512, IN=20, H1=128, H2=64) + head OUT=3.
// Only batch row 511 feeds the output => single-sequence scan.
//
// Pipeline:
//   A : xp1 = x[:,511,:] @ W_ih0^T + b0            (parallel)
//   P : pack W_hh0/W_hh1 f16 TRANSPOSED to global  (parallel, once)
//   B1: layer-1 scan — W via VMEM, h bcast via LDS (serial, 1 CU)
//   C1: xp2 = h1seq @ W_ih1^T + b1                 (parallel GEMM)
//   B2: layer-2 scan — same scheme                  (serial, 1 CU)
//   D : head                                        (parallel)
//
// Round-13: R12 was LDS-ISSUE bound: 256 h-broadcast reads/step dominated
// the one LDS pipe; the W stream shared it. Now W lives ONLY in a packed,
// TRANSPOSED f16 global buffer (wpk[q*1024+r]: lane-stride 16B, perfectly
// coalesced). The 8 loop-invariant W loads either get hoisted to registers
// (demand ~70 < 128 cap) or stream from L2 on the VMEM pipe — either way
// they leave LDS, which now carries only h-broadcasts + partials.
// Numerics unchanged from R11/R12: f16 W, exact hi/lo-f16 h (lo x4096).

#define T_STEPS 1024
#define BATCH   512
#define IN_F    20
#define H1_     128
#define H2_     64
#define OUT_F   3
#define G1_     (4*H1_)   // 512
#define G2_     (4*H2_)   // 256

typedef float f4 __attribute__((ext_vector_type(4)));
typedef unsigned int u32;
typedef u32 u4 __attribute__((ext_vector_type(4)));
typedef _Float16 h2t __attribute__((ext_vector_type(2)));

__device__ __forceinline__ float sigmoidf_(float x) {
    return 1.0f / (1.0f + __expf(-x));
}
__device__ __forceinline__ float tanhf_(float x) {
    return 1.0f - 2.0f / (__expf(2.0f * x) + 1.0f);
}
__device__ __forceinline__ h2t as_h2(u32 v) {
    union { u32 u; h2t h; } c; c.u = v; return c.h;
}
__device__ __forceinline__ u32 pkh(float a, float b) {
    union { _Float16 h[2]; u32 u; } c;
    c.h[0] = (_Float16)a; c.h[1] = (_Float16)b; return c.u;
}
__device__ __forceinline__ float fdot2_(h2t a, h2t b, float c) {
#if __has_builtin(__builtin_amdgcn_fdot2)
    return __builtin_amdgcn_fdot2(a, b, c, false);
#else
    float d = c;
    asm("v_dot2_f32_f16 %0, %1, %2, %0" : "+v"(d) : "v"(a), "v"(b));
    return d;
#endif
}
__device__ __forceinline__ u4 packq(const float* p) {
    const f4 a = *(const f4*)p;
    const f4 b = *(const f4*)(p + 4);
    u4 pk;
    pk.x = pkh(a.x, a.y); pk.y = pkh(a.z, a.w);
    pk.z = pkh(b.x, b.y); pk.w = pkh(b.z, b.w);
    return pk;
}

#define LO_SCALE_INV 0.000244140625f   // 2^-12

// 8 fdot2 against one W quad (hi accum a0/a1, scaled-lo accum a2/a3)
#define DOTQ(WQ, HH, HL)                                                      \
    { const u4 hh_ = (HH); const u4 hl_ = (HL);                               \
      a0 = fdot2_(as_h2((WQ).x), as_h2(hh_.x), a0);                           \
      a1 = fdot2_(as_h2((WQ).y), as_h2(hh_.y), a1);                           \
      a0 = fdot2_(as_h2((WQ).z), as_h2(hh_.z), a0);                           \
      a1 = fdot2_(as_h2((WQ).w), as_h2(hh_.w), a1);                           \
      a2 = fdot2_(as_h2((WQ).x), as_h2(hl_.x), a2);                           \
      a3 = fdot2_(as_h2((WQ).y), as_h2(hl_.y), a3);                           \
      a2 = fdot2_(as_h2((WQ).z), as_h2(hl_.z), a2);                           \
      a3 = fdot2_(as_h2((WQ).w), as_h2(hl_.w), a3); }

// ---------------- A: x-projection for batch row 511 --------------------------
__global__ void xproj_kernel(const float* __restrict__ x,
                             const float* __restrict__ W_ih0,
                             const float* __restrict__ b_ih0,
                             const float* __restrict__ b_hh0,
                             float* __restrict__ xp1)
{
    const int t = blockIdx.x;
    const int g = threadIdx.x;
    const float* xr = x + ((size_t)t * BATCH + (BATCH - 1)) * IN_F;
    const float* w  = W_ih0 + g * IN_F;
    float acc = b_ih0[g] + b_hh0[g];
#pragma unroll
    for (int i = 0; i < IN_F; ++i) acc = fmaf(xr[i], w[i], acc);
    xp1[t * G1_ + g] = acc;
}

// ---------------- P: pack W f16, transposed for coalesced scan reads ---------
// wpk1[q*1024 + r], r=hf*512+g (hf=r>>9,g=r&511), q in [0,8):
//   = W_hh0[g][hf*64 + q*8 .. +8)   (128 KB)
// wpk2[q*1024 + r2], r2=qf*256+g2 (qf=r2>>8,g2=r2&255), q in [0,2):
//   = W_hh1[g2][qf*16 + q*8 .. +8)  (32 KB)
__global__ void pack_kernel(const float* __restrict__ W_hh0,
                            const float* __restrict__ W_hh1,
                            u4* __restrict__ wpk1,
                            u4* __restrict__ wpk2)
{
    const int idx = blockIdx.x * blockDim.x + threadIdx.x;
    if (idx < 8192) {
        const int q = idx >> 10, r = idx & 1023;
        const int g = r & 511, hf = r >> 9;
        wpk1[idx] = packq(W_hh0 + (size_t)g * H1_ + hf * 64 + q * 8);
    } else if (idx < 8192 + 2048) {
        const int i2 = idx - 8192;
        const int q = i2 >> 10, r2 = i2 & 1023;
        const int g2 = r2 & 255, qf = r2 >> 8;
        wpk2[i2] = packq(W_hh1 + (size_t)g2 * H2_ + qf * 16 + q * 8);
    }
}

// ---------------- B1: layer-1 scan (serial, one block) -----------------------
// 1024 thr = 16 waves (4/SIMD). Thread (g=tid&511, hf=tid>>9) owns 64 weights,
// ALL from wpk1 (coalesced VMEM; hoisted to regs or L2-streamed). LDS carries
// only h broadcasts (16/thread) + partials sp1[g*2+hf]. 2 barriers/step.
__global__ __attribute__((amdgpu_flat_work_group_size(1024, 1024),
                          amdgpu_waves_per_eu(4, 4)))
void lstm1_kernel(const float* __restrict__ xp1,
                  const u4* __restrict__ wpk1,
                  float* __restrict__ h1seq)
{
    const int tid = threadIdx.x;
    const int g   = tid & 511;
    const int hf  = tid >> 9;          // wave-uniform
    const int r   = hf * 512 + g;

    __shared__ u4    shhi[16];         // h_hi  f16[128]
    __shared__ u4    shlo[16];         // h_lo*4096 f16[128]
    __shared__ float sp1[1024];        // partials [g*2+hf] (4 KB)

    if (tid < 16) { shhi[tid] = u4{0,0,0,0}; shlo[tid] = u4{0,0,0,0}; }
    float c1 = 0.0f;                   // owned by tid < 128
    __syncthreads();

    const u4* wb = wpk1 + r;           // 8 loop-invariant, coalesced addresses
    float xp_cur = (hf == 0) ? xp1[g] : 0.0f;

    for (int t = 0; t < T_STEPS; ++t) {
        float xp_next = 0.0f;
        if (hf == 0) {
            const int tn = (t + 1 < T_STEPS) ? (t + 1) : (T_STEPS - 1);
            xp_next = xp1[(size_t)tn * G1_ + g];
        }
        const u4 w0_ = wb[0 * 1024], w1_ = wb[1 * 1024];
        const u4 w2_ = wb[2 * 1024], w3_ = wb[3 * 1024];
        const u4 w4_ = wb[4 * 1024], w5_ = wb[5 * 1024];
        const u4 w6_ = wb[6 * 1024], w7_ = wb[7 * 1024];

        float a0 = 0.f, a1 = 0.f, a2 = 0.f, a3 = 0.f;
        DOTQ(w0_, shhi[hf * 8 + 0], shlo[hf * 8 + 0]);
        DOTQ(w1_, shhi[hf * 8 + 1], shlo[hf * 8 + 1]);
        DOTQ(w2_, shhi[hf * 8 + 2], shlo[hf * 8 + 2]);
        DOTQ(w3_, shhi[hf * 8 + 3], shlo[hf * 8 + 3]);
        DOTQ(w4_, shhi[hf * 8 + 4], shlo[hf * 8 + 4]);
        DOTQ(w5_, shhi[hf * 8 + 5], shlo[hf * 8 + 5]);
        DOTQ(w6_, shhi[hf * 8 + 6], shlo[hf * 8 + 6]);
        DOTQ(w7_, shhi[hf * 8 + 7], shlo[hf * 8 + 7]);

        sp1[g * 2 + hf] = ((a0 + a1) + LO_SCALE_INV * (a2 + a3)) + xp_cur;
        __syncthreads();   // partials ready (also orders prev h stores)

        // ---- pointwise (tid<128): combine halves, activate, publish h ------
        if (tid < H1_) {
            const float vi = sp1[tid * 2]              + sp1[tid * 2 + 1];
            const float vf = sp1[(H1_ + tid) * 2]      + sp1[(H1_ + tid) * 2 + 1];
            const float vg = sp1[(2 * H1_ + tid) * 2]  + sp1[(2 * H1_ + tid) * 2 + 1];
            const float vo = sp1[(3 * H1_ + tid) * 2]  + sp1[(3 * H1_ + tid) * 2 + 1];
            c1 = fmaf(sigmoidf_(vf), c1, sigmoidf_(vi) * tanhf_(vg));
            const float h = sigmoidf_(vo) * tanhf_(c1);
            const _Float16 hh16 = (_Float16)h;
            const float hrem = (h - (float)hh16) * 4096.0f;
            ((_Float16*)shhi)[tid] = hh16;
            ((_Float16*)shlo)[tid] = (_Float16)hrem;
            h1seq[(size_t)t * H1_ + tid] = h;   // fire-and-forget (f32 state)
        }
        __syncthreads();   // h f16 arrays ready
        xp_cur = xp_next;
    }
}

// ---------------- C1: xp2 = h1seq @ W_ih1^T + (b_ih1 + b_hh1) ---------------
__global__ void xproj2_kernel(const float* __restrict__ h1seq,
                              const float* __restrict__ W_ih1,
                              const float* __restrict__ b_ih1,
                              const float* __restrict__ b_hh1,
                              float* __restrict__ xp2)
{
    const int t = blockIdx.x;
    const int g = threadIdx.x;
    __shared__ f4 sh[H1_ / 4];
    if (g < H1_ / 4) sh[g] = ((const f4*)(h1seq + (size_t)t * H1_))[g];
    __syncthreads();
    const f4* w = (const f4*)(W_ih1 + (size_t)g * H1_);
    float ax = 0.f, ay = 0.f, az = 0.f, aw = 0.f;
#pragma unroll
    for (int k = 0; k < H1_ / 4; ++k) {
        const f4 h4 = sh[k]; const f4 w4 = w[k];
        ax = fmaf(w4.x, h4.x, ax); ay = fmaf(w4.y, h4.y, ay);
        az = fmaf(w4.z, h4.z, az); aw = fmaf(w4.w, h4.w, aw);
    }
    xp2[(size_t)t * G2_ + g] = ((ax + ay) + (az + aw)) + b_ih1[g] + b_hh1[g];
}

// ---------------- B2: layer-2 scan (serial, one block) -----------------------
// 1024 thr = 16 waves (4/SIMD). Thread (g2=tid&255, qf=tid>>8) owns 16 weights
// (quarter row) from wpk2 (coalesced VMEM). LDS: 4 bcast/wave + sp2[g2*4+qf].
__global__ __attribute__((amdgpu_flat_work_group_size(1024, 1024),
                          amdgpu_waves_per_eu(4, 4)))
void lstm2_kernel(const float* __restrict__ xp2,
                  const u4* __restrict__ wpk2,
                  float* __restrict__ h2seq)
{
    const int tid = threadIdx.x;
    const int g2  = tid & 255;
    const int qf  = tid >> 8;          // wave-uniform quarter

    __shared__ u4    shhi[8];          // h_hi  f16[64]
    __shared__ u4    shlo[8];          // h_lo*4096 f16[64]
    __shared__ float sp2[1024];        // partials [g2*4+qf] (4 KB)

    if (tid < 8) { shhi[tid] = u4{0,0,0,0}; shlo[tid] = u4{0,0,0,0}; }
    float c2 = 0.0f;                   // owned by tid < 64
    __syncthreads();

    const u4* wb = wpk2 + tid;         // 2 loop-invariant, coalesced addresses
    float xp_cur = (qf == 0) ? xp2[g2] : 0.0f;

    for (int t = 0; t < T_STEPS; ++t) {
        float xp_next = 0.0f;
        if (qf == 0) {
            const int tn = (t + 1 < T_STEPS) ? (t + 1) : (T_STEPS - 1);
            xp_next = xp2[(size_t)tn * G2_ + g2];
        }
        const u4 w0_ = wb[0], w1_ = wb[1024];

        float a0 = 0.f, a1 = 0.f, a2 = 0.f, a3 = 0.f;
        DOTQ(w0_, shhi[qf * 2 + 0], shlo[qf * 2 + 0]);
        DOTQ(w1_, shhi[qf * 2 + 1], shlo[qf * 2 + 1]);

        sp2[g2 * 4 + qf] = ((a0 + a1) + LO_SCALE_INV * (a2 + a3)) + xp_cur;
        __syncthreads();   // partials ready (also orders prev h stores)

        // ---- pointwise (tid<64): combine quarters, activate, publish h -----
        if (tid < H2_) {
            const f4 pi = ((const f4*)sp2)[tid];
            const f4 pf = ((const f4*)sp2)[H2_ + tid];
            const f4 pg = ((const f4*)sp2)[2 * H2_ + tid];
            const f4 po = ((const f4*)sp2)[3 * H2_ + tid];
            const float vi = (pi.x + pi.y) + (pi.z + pi.w);
            const float vf = (pf.x + pf.y) + (pf.z + pf.w);
            const float vg = (pg.x + pg.y) + (pg.z + pg.w);
            const float vo = (po.x + po.y) + (po.z + po.w);
            c2 = fmaf(sigmoidf_(vf), c2, sigmoidf_(vi) * tanhf_(vg));
            const float h = sigmoidf_(vo) * tanhf_(c2);
            const _Float16 hh16 = (_Float16)h;
            const float hrem = (h - (float)hh16) * 4096.0f;
            ((_Float16*)shhi)[tid] = hh16;
            ((_Float16*)shlo)[tid] = (_Float16)hrem;
            h2seq[(size_t)t * H2_ + tid] = h;
        }
        __syncthreads();   // h f16 arrays ready
        xp_cur = xp_next;
    }
}

// ---------------- D: head out[t,o] = relu(h2[t]) . W_d[o] + b_d --------------
__global__ void head_kernel(const float* __restrict__ h2seq,
                            const float* __restrict__ W_d,
                            const float* __restrict__ b_d,
                            float* __restrict__ out)
{
    const int idx = blockIdx.x * blockDim.x + threadIdx.x;
    if (idx >= T_STEPS * OUT_F) return;
    const int t = idx / OUT_F;
    const int o = idx - t * OUT_F;
    const float* hr = h2seq + (size_t)t * H2_;
    const float* w  = W_d + o * H2_;
    float acc = b_d[o];
#pragma unroll
    for (int j = 0; j < H2_; ++j) acc = fmaf(fmaxf(hr[j], 0.0f), w[j], acc);
    out[idx] = acc;
}

extern "C" void kernel_launch(void* const* d_in, const int* in_sizes, int n_in,
                              void* d_out, int out_size, void* d_ws, size_t ws_size,
                              hipStream_t stream) {
    const float* x     = (const float*)d_in[0];
    const float* W_ih0 = (const float*)d_in[1];
    const float* W_hh0 = (const float*)d_in[2];
    const float* b_ih0 = (const float*)d_in[3];
    const float* b_hh0 = (const float*)d_in[4];
    const float* W_ih1 = (const float*)d_in[5];
    const float* W_hh1 = (const float*)d_in[6];
    const float* b_ih1 = (const float*)d_in[7];
    const float* b_hh1 = (const float*)d_in[8];
    const float* W_d   = (const float*)d_in[9];
    const float* b_d   = (const float*)d_in[10];

    float* out   = (float*)d_out;
    float* xp1   = (float*)d_ws;                         // [1024][512] = 2 MB
    float* h1seq = xp1 + (size_t)T_STEPS * G1_;          // [1024][128] = 512 KB
    float* h2seq = h1seq + (size_t)T_STEPS * H1_;        // [1024][64]  = 256 KB
    u4*    wpk1  = (u4*)(h2seq + (size_t)T_STEPS * H2_); // 8192*16B = 128 KB
    u4*    wpk2  = wpk1 + 8192;                          // 2048*16B =  32 KB
    float* xp2   = xp1;                                  // overlay (xp1 dead after B1)

    hipLaunchKernelGGL(xproj_kernel, dim3(T_STEPS), dim3(G1_), 0, stream,
                       x, W_ih0, b_ih0, b_hh0, xp1);
    hipLaunchKernelGGL(pack_kernel, dim3(40), dim3(256), 0, stream,
                       W_hh0, W_hh1, wpk1, wpk2);
    hipLaunchKernelGGL(lstm1_kernel, dim3(1), dim3(1024), 0, stream,
                       xp1, wpk1, h1seq);
    hipLaunchKernelGGL(xproj2_kernel, dim3(T_STEPS), dim3(G2_), 0, stream,
                       h1seq, W_ih1, b_ih1, b_hh1, xp2);
    hipLaunchKernelGGL(lstm2_kernel, dim3(1), dim3(1024), 0, stream,
                       xp2, wpk2, h2seq);
    hipLaunchKernelGGL(head_kernel, dim3((T_STEPS * OUT_F + 255) / 256), dim3(256),
                       0, stream, h2seq, W_d, b_d, out);
}